// Round 3
// baseline (973.117 us; speedup 1.0000x reference)
//
#include <hip/hip_runtime.h>
#include <hip/hip_bf16.h>
#include <math.h>

#define D_MODEL 2048
#define N_HEADS 16
#define D_HEAD  128
#define BATCH   64
#define SEQ     128
#define BT      (BATCH*SEQ)   // 8192 rows

typedef __bf16 bf16;
typedef __attribute__((ext_vector_type(8))) __bf16 bf16x8;
typedef __attribute__((ext_vector_type(4))) float  f32x4;

__device__ __forceinline__ f32x4 mfma16(bf16x8 a, bf16x8 b, f32x4 c) {
    return __builtin_amdgcn_mfma_f32_16x16x32_bf16(a, b, c, 0, 0, 0);
}

// load 8 contiguous fp32, convert to bf16x8 (RNE via hw cvt)
__device__ __forceinline__ bf16x8 cvt8_f32(const float* p) {
    f32x4 lo = *(const f32x4*)p;
    f32x4 hi = *(const f32x4*)(p + 4);
    bf16x8 r;
    r[0] = (bf16)lo[0]; r[1] = (bf16)lo[1]; r[2] = (bf16)lo[2]; r[3] = (bf16)lo[3];
    r[4] = (bf16)hi[0]; r[5] = (bf16)hi[1]; r[6] = (bf16)hi[2]; r[7] = (bf16)hi[3];
    return r;
}

// ---------------------------------------------------------------------------
// C[M,N] = X[M,K] @ W[N,K]^T  (row-major, contract over contiguous K).
// X/W fp32 or bf16 per template; staged to LDS as bf16. Output type OutT.
// 64x64 tile, BK=32, 256 threads = 4 waves in 2x2, each wave 32x32 (2x2 mfma).
// ---------------------------------------------------------------------------
template<bool AF32, bool BF32, typename OutT>
__global__ __launch_bounds__(256) void gemm_nt(const void* __restrict__ Xv,
                                               const void* __restrict__ Wv,
                                               OutT* __restrict__ C,
                                               int M, int N, int K)
{
    // stride 40 elems = 80 B: 16B-aligned rows, bank offset 20/row -> 2-way (free)
    __shared__ __align__(16) bf16 As[64 * 40];
    __shared__ __align__(16) bf16 Bs[64 * 40];

    const int tid  = threadIdx.x;
    const int w    = tid >> 6;
    const int l    = tid & 63;
    const int quad = l >> 4;
    const int ln   = l & 15;
    const int wm   = w >> 1;
    const int wn   = w & 1;

    const size_t mbase = (size_t)blockIdx.y * 64;
    const size_t nbase = (size_t)blockIdx.x * 64;

    const int srow = tid >> 2;          // 0..63
    const int scg  = (tid & 3) * 8;     // 0,8,16,24

    const size_t xoff = (mbase + srow) * (size_t)K + scg;
    const size_t woff = (nbase + srow) * (size_t)K + scg;

    f32x4 acc[2][2];
    for (int i = 0; i < 2; ++i)
        for (int j = 0; j < 2; ++j)
            acc[i][j] = (f32x4){0.f, 0.f, 0.f, 0.f};

    for (int k = 0; k < K; k += 32) {
        bf16x8 xa, wb;
        if (AF32) xa = cvt8_f32((const float*)Xv + xoff + k);
        else      xa = *(const bf16x8*)((const bf16*)Xv + xoff + k);
        if (BF32) wb = cvt8_f32((const float*)Wv + woff + k);
        else      wb = *(const bf16x8*)((const bf16*)Wv + woff + k);
        *(bf16x8*)&As[srow * 40 + scg] = xa;
        *(bf16x8*)&Bs[srow * 40 + scg] = wb;
        __syncthreads();

        bf16x8 a0 = *(const bf16x8*)&As[(wm * 32 +      ln) * 40 + quad * 8];
        bf16x8 a1 = *(const bf16x8*)&As[(wm * 32 + 16 + ln) * 40 + quad * 8];
        bf16x8 b0 = *(const bf16x8*)&Bs[(wn * 32 +      ln) * 40 + quad * 8];
        bf16x8 b1 = *(const bf16x8*)&Bs[(wn * 32 + 16 + ln) * 40 + quad * 8];

        acc[0][0] = mfma16(a0, b0, acc[0][0]);
        acc[0][1] = mfma16(a0, b1, acc[0][1]);
        acc[1][0] = mfma16(a1, b0, acc[1][0]);
        acc[1][1] = mfma16(a1, b1, acc[1][1]);
        __syncthreads();
    }

    // C/D layout: col = ln, row = quad*4 + r (m89/m91-verified)
    for (int st = 0; st < 2; ++st)
        for (int sn = 0; sn < 2; ++sn)
            for (int r = 0; r < 4; ++r) {
                size_t row = mbase + wm * 32 + st * 16 + quad * 4 + r;
                size_t col = nbase + wn * 32 + sn * 16 + ln;
                C[row * (size_t)N + col] = (OutT)acc[st][sn][r];
            }
}

// ---------------------------------------------------------------------------
// In-place RoPE over a (BT, D_MODEL) bf16 buffer laid out (b,t,h,d).
// ---------------------------------------------------------------------------
__global__ __launch_bounds__(256) void rope_kernel(bf16* __restrict__ Qk)
{
    int idx = blockIdx.x * 256 + threadIdx.x;   // < 8,388,608
    int row = idx >> 10;
    int pp  = idx & 1023;
    int h   = pp >> 6;
    int i   = pp & 63;
    int t   = row & (SEQ - 1);

    float theta = __expf((float)(2 * i) * (-9.210340371976184f / 128.0f));
    float ang   = (float)t * theta;
    float sn, cs;
    sincosf(ang, &sn, &cs);

    size_t a = (size_t)row * D_MODEL + h * D_HEAD + 2 * i;
    float e = (float)Qk[a];
    float o = (float)Qk[a + 1];
    Qk[a]     = (bf16)(e * cs - o * sn);
    Qk[a + 1] = (bf16)(e * sn + o * cs);
}

// ---------------------------------------------------------------------------
// Attention core: one workgroup per (b,h). T = Dh = 128. All-finite math.
// ---------------------------------------------------------------------------
__global__ __launch_bounds__(256) void attn_kernel(const bf16* __restrict__ Q,
                                                   const bf16* __restrict__ K,
                                                   const bf16* __restrict__ V,
                                                   bf16* __restrict__ O)
{
    __shared__ __align__(16) bf16 P_lds[128 * 136];
    __shared__ __align__(16) bf16 Vt_lds[128 * 136];

    const int bh = blockIdx.x;
    const int b  = bh >> 4;
    const int h  = bh & 15;
    const size_t base = (size_t)b * SEQ * D_MODEL + (size_t)h * D_HEAD;

    const int tid  = threadIdx.x;
    const int w    = tid >> 6;
    const int l    = tid & 63;
    const int quad = l >> 4;
    const int ln   = l & 15;

    // stage V^T: Vt[d][k] = V[k][d]
    {
        int k  = tid >> 1;
        int d0 = (tid & 1) * 64;
        const bf16* vp = V + base + (size_t)k * D_MODEL + d0;
        for (int c = 0; c < 8; ++c) {
            bf16x8 v = *(const bf16x8*)(vp + c * 8);
            for (int j = 0; j < 8; ++j)
                Vt_lds[(d0 + c * 8 + j) * 136 + k] = v[j];
        }
    }

    const float rscale = 0.08838834764831845f;   // 1/sqrt(128)
    const float NEG    = -1e30f;                 // finite mask value

    for (int s = 0; s < 2; ++s) {
        const int q0 = w * 32 + s * 16;
        f32x4 acc[8];
        for (int nt = 0; nt < 8; ++nt) acc[nt] = (f32x4){0.f, 0.f, 0.f, 0.f};

        for (int kt = 0; kt < 4; ++kt) {
            bf16x8 a = *(const bf16x8*)(Q + base + (size_t)(q0 + ln) * D_MODEL
                                          + kt * 32 + quad * 8);
            for (int nt = 0; nt < 8; ++nt) {
                bf16x8 bb = *(const bf16x8*)(K + base
                                 + (size_t)(nt * 16 + ln) * D_MODEL
                                 + kt * 32 + quad * 8);
                acc[nt] = mfma16(a, bb, acc[nt]);
            }
        }

        float mx[4] = {NEG, NEG, NEG, NEG};
        for (int nt = 0; nt < 8; ++nt)
            for (int r = 0; r < 4; ++r) {
                int q = q0 + quad * 4 + r;
                int c = nt * 16 + ln;
                float v = acc[nt][r] * rscale;
                v = (c <= q) ? v : NEG;
                acc[nt][r] = v;
                mx[r] = fmaxf(mx[r], v);
            }
        for (int m = 1; m < 16; m <<= 1)
            for (int r = 0; r < 4; ++r)
                mx[r] = fmaxf(mx[r], __shfl_xor(mx[r], m));

        float sm[4] = {0.f, 0.f, 0.f, 0.f};
        for (int nt = 0; nt < 8; ++nt)
            for (int r = 0; r < 4; ++r) {
                float p = __expf(acc[nt][r] - mx[r]);
                acc[nt][r] = p;
                sm[r] += p;
            }
        for (int m = 1; m < 16; m <<= 1)
            for (int r = 0; r < 4; ++r)
                sm[r] += __shfl_xor(sm[r], m);

        float inv[4];
        for (int r = 0; r < 4; ++r) inv[r] = 1.0f / sm[r];

        for (int nt = 0; nt < 8; ++nt)
            for (int r = 0; r < 4; ++r) {
                int q = q0 + quad * 4 + r;
                int c = nt * 16 + ln;
                P_lds[q * 136 + c] = (bf16)(acc[nt][r] * inv[r]);
            }
    }

    __syncthreads();

    f32x4 o[2][8];
    for (int s = 0; s < 2; ++s)
        for (int nt = 0; nt < 8; ++nt) o[s][nt] = (f32x4){0.f, 0.f, 0.f, 0.f};

    for (int kt = 0; kt < 4; ++kt) {
        bf16x8 a0 = *(const bf16x8*)&P_lds[(w * 32 +      ln) * 136 + kt * 32 + quad * 8];
        bf16x8 a1 = *(const bf16x8*)&P_lds[(w * 32 + 16 + ln) * 136 + kt * 32 + quad * 8];
        for (int nt = 0; nt < 8; ++nt) {
            bf16x8 bb = *(const bf16x8*)&Vt_lds[(nt * 16 + ln) * 136 + kt * 32 + quad * 8];
            o[0][nt] = mfma16(a0, bb, o[0][nt]);
            o[1][nt] = mfma16(a1, bb, o[1][nt]);
        }
    }

    for (int s = 0; s < 2; ++s)
        for (int nt = 0; nt < 8; ++nt)
            for (int r = 0; r < 4; ++r) {
                int q = w * 32 + s * 16 + quad * 4 + r;
                int d = nt * 16 + ln;
                O[base + (size_t)q * D_MODEL + d] = (bf16)o[s][nt][r];
            }
}

// ---------------------------------------------------------------------------
extern "C" void kernel_launch(void* const* d_in, const int* in_sizes, int n_in,
                              void* d_out, int out_size, void* d_ws, size_t ws_size,
                              hipStream_t stream)
{
    // Reference dtypes: ALL float32 (inputs AND output).
    const void* x  = d_in[0];
    const void* Wq = d_in[1];
    const void* Wk = d_in[2];
    const void* Wv = d_in[3];
    const void* Wo = d_in[4];
    // d_in[5] = causal mask -- hardcoded in attn_kernel.
    float* out = (float*)d_out;   // reference output dtype is float32

    const size_t elems = (size_t)BT * D_MODEL;   // 16,777,216
    bf16* Q  = (bf16*)d_ws;
    bf16* Kb = Q + elems;
    bf16* Vb = Kb + elems;                        // ws use: 96 MiB

    dim3 g(D_MODEL / 64, BT / 64);   // (32, 128)

    gemm_nt<true, true, bf16><<<g, 256, 0, stream>>>(x, Wq, Q,  BT, D_MODEL, D_MODEL);
    gemm_nt<true, true, bf16><<<g, 256, 0, stream>>>(x, Wk, Kb, BT, D_MODEL, D_MODEL);
    gemm_nt<true, true, bf16><<<g, 256, 0, stream>>>(x, Wv, Vb, BT, D_MODEL, D_MODEL);

    rope_kernel<<<(BT * (D_MODEL / 2)) / 256, 256, 0, stream>>>(Q);
    rope_kernel<<<(BT * (D_MODEL / 2)) / 256, 256, 0, stream>>>(Kb);

    attn_kernel<<<BATCH * N_HEADS, 256, 0, stream>>>(Q, Kb, Vb, Q);

    gemm_nt<false, true, float><<<g, 256, 0, stream>>>(Q, Wo, out, BT, D_MODEL, D_MODEL);
}

// Round 4
// 604.218 us; speedup vs baseline: 1.6105x; 1.6105x over previous
//
#include <hip/hip_runtime.h>
#include <hip/hip_bf16.h>
#include <math.h>

#define D_MODEL 2048
#define N_HEADS 16
#define D_HEAD  128
#define BATCH   64
#define SEQ     128
#define BT      (BATCH*SEQ)   // 8192 rows
#define LDF     6144          // fused QKV row stride
#define KOFF    2048
#define VOFF    4096

typedef __bf16 bf16;
typedef __attribute__((ext_vector_type(8))) __bf16 bf16x8;
typedef __attribute__((ext_vector_type(4))) float  f32x4;

__device__ __forceinline__ f32x4 mfma16(bf16x8 a, bf16x8 b, f32x4 c) {
    return __builtin_amdgcn_mfma_f32_16x16x32_bf16(a, b, c, 0, 0, 0);
}

__device__ __forceinline__ bf16x8 cvt8_f32(const float* p) {
    f32x4 lo = *(const f32x4*)p;
    f32x4 hi = *(const f32x4*)(p + 4);
    bf16x8 r;
    r[0] = (bf16)lo[0]; r[1] = (bf16)lo[1]; r[2] = (bf16)lo[2]; r[3] = (bf16)lo[3];
    r[4] = (bf16)hi[0]; r[5] = (bf16)hi[1]; r[6] = (bf16)hi[2]; r[7] = (bf16)hi[3];
    return r;
}

// async global->LDS, 16 B/lane; LDS dest = wave-uniform base + lane*16 (m104)
__device__ __forceinline__ void gl2lds16(const bf16* g, bf16* l) {
    __builtin_amdgcn_global_load_lds(
        (const __attribute__((address_space(1))) void*)g,
        (__attribute__((address_space(3))) void*)l, 16, 0, 0);
}

// ---------------------------------------------------------------------------
// fp32 -> bf16 elementwise convert, 8 elems/thread
// ---------------------------------------------------------------------------
__global__ __launch_bounds__(256) void cvt_kernel(const float* __restrict__ src,
                                                  bf16* __restrict__ dst, int n8)
{
    int i = blockIdx.x * 256 + threadIdx.x;
    if (i < n8) *(bf16x8*)(dst + (size_t)i * 8) = cvt8_f32(src + (size_t)i * 8);
}

// ---------------------------------------------------------------------------
// m97-structure GEMM: C[M,N] = A[M,K] @ B[N,K]^T, bf16 in, OutT out.
// 128x128 tile, BK=32, 256 thr = 4 waves (2x2), each wave 64x64 (4x4 mfma).
// LDS tiles unpadded row-major (global_load_lds lane-order constraint).
// ---------------------------------------------------------------------------
template<typename OutT>
__global__ __launch_bounds__(256) void gemm128(const bf16* __restrict__ A,
                                               const bf16* __restrict__ B,
                                               OutT* __restrict__ C,
                                               int lda, int ldb, int ldc, int K)
{
    __shared__ __align__(16) bf16 As[128 * 32];   // 8 KB
    __shared__ __align__(16) bf16 Bs[128 * 32];   // 8 KB

    const int tid  = threadIdx.x;
    const int w    = tid >> 6;
    const int l    = tid & 63;
    const int quad = l >> 4;
    const int ln   = l & 15;
    const int wm   = w >> 1;
    const int wn   = w & 1;

    const size_t mbase = (size_t)blockIdx.y * 128;
    const size_t nbase = (size_t)blockIdx.x * 128;

    // staging: thread t -> row t>>2, colgroup (t&3)*8; LDS offset = t*16 B
    const int srow = tid >> 2;          // 0..63
    const int scg  = (tid & 3) * 8;

    const bf16* Ap0 = A + (mbase + srow) * (size_t)lda + scg;
    const bf16* Ap1 = Ap0 + 64 * (size_t)lda;
    const bf16* Bp0 = B + (nbase + srow) * (size_t)ldb + scg;
    const bf16* Bp1 = Bp0 + 64 * (size_t)ldb;

    bf16* asl0 = &As[w * 512];          // wave-uniform LDS bases
    bf16* asl1 = &As[2048 + w * 512];
    bf16* bsl0 = &Bs[w * 512];
    bf16* bsl1 = &Bs[2048 + w * 512];

    f32x4 acc[4][4];
    for (int i = 0; i < 4; ++i)
        for (int j = 0; j < 4; ++j)
            acc[i][j] = (f32x4){0.f, 0.f, 0.f, 0.f};

    for (int k0 = 0; k0 < K; k0 += 32) {
        gl2lds16(Ap0 + k0, asl0);
        gl2lds16(Ap1 + k0, asl1);
        gl2lds16(Bp0 + k0, bsl0);
        gl2lds16(Bp1 + k0, bsl1);
        __syncthreads();

        bf16x8 af[4], bf[4];
        for (int i = 0; i < 4; ++i)
            af[i] = *(const bf16x8*)&As[(wm * 64 + i * 16 + ln) * 32 + quad * 8];
        for (int j = 0; j < 4; ++j)
            bf[j] = *(const bf16x8*)&Bs[(wn * 64 + j * 16 + ln) * 32 + quad * 8];

        for (int i = 0; i < 4; ++i)
            for (int j = 0; j < 4; ++j)
                acc[i][j] = mfma16(af[i], bf[j], acc[i][j]);
        __syncthreads();
    }

    // C/D: col = ln, row = quad*4 + r  (m89/m91-verified)
    for (int i = 0; i < 4; ++i)
        for (int j = 0; j < 4; ++j)
            for (int r = 0; r < 4; ++r) {
                size_t row = mbase + wm * 64 + i * 16 + quad * 4 + r;
                size_t col = nbase + wn * 64 + j * 16 + ln;
                C[row * (size_t)ldc + col] = (OutT)acc[i][j][r];
            }
}

// ---------------------------------------------------------------------------
// RoPE over fused buffer cols 0..4095 (Q heads then K heads), stride LDF.
// One thread per pair; pair count = BT * 2048.
// ---------------------------------------------------------------------------
__global__ __launch_bounds__(256) void rope_fused(bf16* __restrict__ buf)
{
    int idx = blockIdx.x * 256 + threadIdx.x;   // < 16,777,216
    int row = idx >> 11;          // 0..8191
    int pc  = idx & 2047;         // pair-col; col = 2*pc in [0,4096)
    int i   = pc & 63;            // within-head pair index
    int t   = row & (SEQ - 1);

    float theta = __expf((float)(2 * i) * (-9.210340371976184f / 128.0f));
    float ang   = (float)t * theta;
    float sn, cs;
    sincosf(ang, &sn, &cs);

    size_t a = (size_t)row * LDF + 2 * pc;
    float e = (float)buf[a];
    float o = (float)buf[a + 1];
    buf[a]     = (bf16)(e * cs - o * sn);
    buf[a + 1] = (bf16)(e * sn + o * cs);
}

// ---------------------------------------------------------------------------
// Attention over the fused buffer. One workgroup per (b,h). T = Dh = 128.
// Q at col h*128, K at KOFF+h*128, V at VOFF+h*128; O written over Q cols.
// ---------------------------------------------------------------------------
__global__ __launch_bounds__(256) void attn_kernel(bf16* __restrict__ buf)
{
    __shared__ __align__(16) bf16 P_lds[128 * 136];
    __shared__ __align__(16) bf16 Vt_lds[128 * 136];

    const int bh = blockIdx.x;
    const int b  = bh >> 4;
    const int h  = bh & 15;
    const size_t baseQ = (size_t)b * SEQ * LDF + (size_t)h * D_HEAD;
    const size_t baseK = baseQ + KOFF;
    const size_t baseV = baseQ + VOFF;

    const int tid  = threadIdx.x;
    const int w    = tid >> 6;
    const int l    = tid & 63;
    const int quad = l >> 4;
    const int ln   = l & 15;

    // stage V^T: Vt[d][k] = V[k][d]
    {
        int k  = tid >> 1;
        int d0 = (tid & 1) * 64;
        const bf16* vp = buf + baseV + (size_t)k * LDF + d0;
        for (int c = 0; c < 8; ++c) {
            bf16x8 v = *(const bf16x8*)(vp + c * 8);
            for (int j = 0; j < 8; ++j)
                Vt_lds[(d0 + c * 8 + j) * 136 + k] = v[j];
        }
    }

    const float rscale = 0.08838834764831845f;   // 1/sqrt(128)
    const float NEG    = -1e30f;

    for (int s = 0; s < 2; ++s) {
        const int q0 = w * 32 + s * 16;
        f32x4 acc[8];
        for (int nt = 0; nt < 8; ++nt) acc[nt] = (f32x4){0.f, 0.f, 0.f, 0.f};

        for (int kt = 0; kt < 4; ++kt) {
            bf16x8 a = *(const bf16x8*)(buf + baseQ + (size_t)(q0 + ln) * LDF
                                          + kt * 32 + quad * 8);
            for (int nt = 0; nt < 8; ++nt) {
                bf16x8 bb = *(const bf16x8*)(buf + baseK
                                 + (size_t)(nt * 16 + ln) * LDF
                                 + kt * 32 + quad * 8);
                acc[nt] = mfma16(a, bb, acc[nt]);
            }
        }

        float mx[4] = {NEG, NEG, NEG, NEG};
        for (int nt = 0; nt < 8; ++nt)
            for (int r = 0; r < 4; ++r) {
                int q = q0 + quad * 4 + r;
                int c = nt * 16 + ln;
                float v = acc[nt][r] * rscale;
                v = (c <= q) ? v : NEG;
                acc[nt][r] = v;
                mx[r] = fmaxf(mx[r], v);
            }
        for (int m = 1; m < 16; m <<= 1)
            for (int r = 0; r < 4; ++r)
                mx[r] = fmaxf(mx[r], __shfl_xor(mx[r], m));

        float sm[4] = {0.f, 0.f, 0.f, 0.f};
        for (int nt = 0; nt < 8; ++nt)
            for (int r = 0; r < 4; ++r) {
                float p = __expf(acc[nt][r] - mx[r]);
                acc[nt][r] = p;
                sm[r] += p;
            }
        for (int m = 1; m < 16; m <<= 1)
            for (int r = 0; r < 4; ++r)
                sm[r] += __shfl_xor(sm[r], m);

        float inv[4];
        for (int r = 0; r < 4; ++r) inv[r] = 1.0f / sm[r];

        for (int nt = 0; nt < 8; ++nt)
            for (int r = 0; r < 4; ++r) {
                int q = q0 + quad * 4 + r;
                int c = nt * 16 + ln;
                P_lds[q * 136 + c] = (bf16)(acc[nt][r] * inv[r]);
            }
    }

    __syncthreads();   // Vt staging + (own-rows) P complete

    f32x4 o[2][8];
    for (int s = 0; s < 2; ++s)
        for (int nt = 0; nt < 8; ++nt) o[s][nt] = (f32x4){0.f, 0.f, 0.f, 0.f};

    for (int kt = 0; kt < 4; ++kt) {
        bf16x8 a0 = *(const bf16x8*)&P_lds[(w * 32 +      ln) * 136 + kt * 32 + quad * 8];
        bf16x8 a1 = *(const bf16x8*)&P_lds[(w * 32 + 16 + ln) * 136 + kt * 32 + quad * 8];
        for (int nt = 0; nt < 8; ++nt) {
            bf16x8 bb = *(const bf16x8*)&Vt_lds[(nt * 16 + ln) * 136 + kt * 32 + quad * 8];
            o[0][nt] = mfma16(a0, bb, o[0][nt]);
            o[1][nt] = mfma16(a1, bb, o[1][nt]);
        }
    }

    for (int s = 0; s < 2; ++s)
        for (int nt = 0; nt < 8; ++nt)
            for (int r = 0; r < 4; ++r) {
                int q = w * 32 + s * 16 + quad * 4 + r;
                int d = nt * 16 + ln;
                buf[baseQ + (size_t)q * LDF + d] = (bf16)o[s][nt][r];
            }
}

// ---------------------------------------------------------------------------
extern "C" void kernel_launch(void* const* d_in, const int* in_sizes, int n_in,
                              void* d_out, int out_size, void* d_ws, size_t ws_size,
                              hipStream_t stream)
{
    const float* x  = (const float*)d_in[0];
    const float* Wq = (const float*)d_in[1];
    const float* Wk = (const float*)d_in[2];
    const float* Wv = (const float*)d_in[3];
    const float* Wo = (const float*)d_in[4];
    float* out = (float*)d_out;

    // ws layout (bf16 elems):
    //   QKVbuf: BT*6144            = 50,331,648   (100.7 MB)
    //   xb:     BT*2048            = 16,777,216   ( 33.6 MB)  [Wo reuses after GEMM1]
    //   WB:     6144*2048          = 12,582,912   ( 25.2 MB)
    bf16* QKV = (bf16*)d_ws;
    bf16* xb  = QKV + (size_t)BT * LDF;
    bf16* WB  = xb + (size_t)BT * D_MODEL;
    bf16* WoB = xb;                               // overlaps xb (free after GEMM1)

    const int n8x = BT * D_MODEL / 8;             // 2,097,152
    const int n8w = D_MODEL * D_MODEL / 8;        //   524,288

    cvt_kernel<<<(n8x + 255) / 256, 256, 0, stream>>>(x,  xb, n8x);
    cvt_kernel<<<(n8w + 255) / 256, 256, 0, stream>>>(Wq, WB,            n8w);
    cvt_kernel<<<(n8w + 255) / 256, 256, 0, stream>>>(Wk, WB + n8w * 8,  n8w);
    cvt_kernel<<<(n8w + 255) / 256, 256, 0, stream>>>(Wv, WB + (size_t)n8w * 16, n8w);

    // fused QKV projection: [8192 x 6144] = xb @ WB^T
    dim3 g1(LDF / 128, BT / 128);   // (48, 64)
    gemm128<bf16><<<g1, 256, 0, stream>>>(xb, WB, QKV, D_MODEL, D_MODEL, LDF, D_MODEL);

    // Wo convert (into xb region, now free)
    cvt_kernel<<<(n8w + 255) / 256, 256, 0, stream>>>(Wo, WoB, n8w);

    // RoPE on Q|K columns (0..4095)
    rope_fused<<<(BT * 2048) / 256, 256, 0, stream>>>(QKV);

    // attention, O in-place over Q columns
    attn_kernel<<<BATCH * N_HEADS, 256, 0, stream>>>(QKV);

    // output projection: out[8192 x 2048] = O @ Wo^T  (fp32 out)
    dim3 g2(D_MODEL / 128, BT / 128);  // (16, 64)
    gemm128<float><<<g2, 256, 0, stream>>>(QKV, WoB, out, LDF, D_MODEL, D_MODEL, D_MODEL);
}

// Round 5
// 532.090 us; speedup vs baseline: 1.8289x; 1.1356x over previous
//
#include <hip/hip_runtime.h>
#include <hip/hip_bf16.h>
#include <math.h>

#define D_MODEL 2048
#define N_HEADS 16
#define D_HEAD  128
#define BATCH   64
#define SEQ     128
#define BT      (BATCH*SEQ)   // 8192 rows
#define LDF     6144          // fused QKV row stride
#define KOFF    2048
#define VOFF    4096

typedef __bf16 bf16;
typedef __attribute__((ext_vector_type(8))) __bf16 bf16x8;
typedef __attribute__((ext_vector_type(4))) float  f32x4;

__device__ __forceinline__ f32x4 mfma16(bf16x8 a, bf16x8 b, f32x4 c) {
    return __builtin_amdgcn_mfma_f32_16x16x32_bf16(a, b, c, 0, 0, 0);
}

__device__ __forceinline__ bf16x8 cvt8_f32(const float* p) {
    f32x4 lo = *(const f32x4*)p;
    f32x4 hi = *(const f32x4*)(p + 4);
    bf16x8 r;
    r[0] = (bf16)lo[0]; r[1] = (bf16)lo[1]; r[2] = (bf16)lo[2]; r[3] = (bf16)lo[3];
    r[4] = (bf16)hi[0]; r[5] = (bf16)hi[1]; r[6] = (bf16)hi[2]; r[7] = (bf16)hi[3];
    return r;
}

// async global->LDS, 16 B/lane; LDS dest = wave-uniform base + lane*16 (m104)
__device__ __forceinline__ void gl2lds16(const bf16* g, bf16* l) {
    __builtin_amdgcn_global_load_lds(
        (const __attribute__((address_space(1))) void*)g,
        (__attribute__((address_space(3))) void*)l, 16, 0, 0);
}

// rope 8 consecutive d-elements (4 even/odd pairs); tpos = seq position,
// pair0 = global pair index of element 0. exp/sincos in fp32.
__device__ __forceinline__ bf16x8 rope8(bf16x8 v, int tpos, int pair0) {
    bf16x8 r;
    for (int m = 0; m < 4; ++m) {
        int i = pair0 + m;
        float theta = __expf((float)(2 * i) * (-9.210340371976184f / 128.0f));
        float ang   = (float)tpos * theta;
        float sn, cs;
        __sincosf(ang, &sn, &cs);
        float e = (float)v[2 * m], o = (float)v[2 * m + 1];
        r[2 * m]     = (bf16)(e * cs - o * sn);
        r[2 * m + 1] = (bf16)(e * sn + o * cs);
    }
    return r;
}

// ---------------------------------------------------------------------------
// fp32 -> bf16 elementwise convert, 8 elems/thread
// ---------------------------------------------------------------------------
__global__ __launch_bounds__(256) void cvt_kernel(const float* __restrict__ src,
                                                  bf16* __restrict__ dst, int n8)
{
    int i = blockIdx.x * 256 + threadIdx.x;
    if (i < n8) *(bf16x8*)(dst + (size_t)i * 8) = cvt8_f32(src + (size_t)i * 8);
}

// 3 weight matrices in one launch: sel = i>>19 (n8w = 2^19 per matrix)
__global__ __launch_bounds__(256) void cvt_w3(const float* __restrict__ w0,
                                              const float* __restrict__ w1,
                                              const float* __restrict__ w2,
                                              bf16* __restrict__ dst)
{
    int i   = blockIdx.x * 256 + threadIdx.x;     // < 3*2^19
    int sel = i >> 19;
    int off = i & ((1 << 19) - 1);
    const float* s = (sel == 0) ? w0 : (sel == 1) ? w1 : w2;
    *(bf16x8*)(dst + (size_t)i * 8) = cvt8_f32(s + (size_t)off * 8);
}

// ---------------------------------------------------------------------------
// GEMM: C[M,N] = A[M,K] @ B[N,K]^T, bf16 in, OutT out.
// 128x128 tile, BK=64 (32 MFMA per barrier-pair), 256 thr = 4 waves (2x2).
// LDS: xor-swizzled 16B chunks (phys = logical ^ (row&7)) -> 2-way banks max,
// staged via global_load_lds with per-lane swizzled GLOBAL addresses so the
// lane-ordered LDS constraint (m104) is honored.
// ---------------------------------------------------------------------------
template<typename OutT>
__global__ __launch_bounds__(256) void gemm128(const bf16* __restrict__ A,
                                               const bf16* __restrict__ B,
                                               OutT* __restrict__ C,
                                               int lda, int ldb, int ldc, int K)
{
    __shared__ __align__(16) bf16 As[128 * 64];   // 16 KB
    __shared__ __align__(16) bf16 Bs[128 * 64];   // 16 KB

    const int tid  = threadIdx.x;
    const int w    = tid >> 6;
    const int l    = tid & 63;
    const int quad = l >> 4;
    const int ln   = l & 15;
    const int wm   = w >> 1;
    const int wn   = w & 1;

    const size_t mbase = (size_t)blockIdx.y * 128;
    const size_t nbase = (size_t)blockIdx.x * 128;

    // staging: call c covers rows c*32..c*32+31. thread t -> row c*32+(t>>3),
    // logical 8-elem chunk (t&7)^((t>>3)&7)  [xor-swizzle]
    const int srow8  = tid >> 3;                        // 0..31
    const int schunk = (tid & 7) ^ (srow8 & 7);         // logical chunk 0..7

    const bf16* Ap = A + (mbase + srow8) * (size_t)lda + schunk * 8;
    const bf16* Bp = B + (nbase + srow8) * (size_t)ldb + schunk * 8;

    f32x4 acc[4][4];
    for (int i = 0; i < 4; ++i)
        for (int j = 0; j < 4; ++j)
            acc[i][j] = (f32x4){0.f, 0.f, 0.f, 0.f};

    const int xr = ln & 7;   // read-side xor term (row&7 == ln&7)

    for (int k0 = 0; k0 < K; k0 += 64) {
        for (int c = 0; c < 4; ++c) {
            gl2lds16(Ap + (size_t)c * 32 * lda + k0, &As[c * 2048 + w * 512]);
            gl2lds16(Bp + (size_t)c * 32 * ldb + k0, &Bs[c * 2048 + w * 512]);
        }
        __syncthreads();

        for (int kk = 0; kk < 2; ++kk) {
            bf16x8 af[4], bfr[4];
            const int sw = ((kk * 4 + quad) ^ xr) * 8;
            for (int i = 0; i < 4; ++i)
                af[i] = *(const bf16x8*)&As[(wm * 64 + i * 16 + ln) * 64 + sw];
            for (int j = 0; j < 4; ++j)
                bfr[j] = *(const bf16x8*)&Bs[(wn * 64 + j * 16 + ln) * 64 + sw];
            for (int i = 0; i < 4; ++i)
                for (int j = 0; j < 4; ++j)
                    acc[i][j] = mfma16(af[i], bfr[j], acc[i][j]);
        }
        __syncthreads();
    }

    // C/D: col = ln, row = quad*4 + r  (m89/m91-verified)
    for (int i = 0; i < 4; ++i)
        for (int j = 0; j < 4; ++j)
            for (int r = 0; r < 4; ++r) {
                size_t row = mbase + wm * 64 + i * 16 + quad * 4 + r;
                size_t col = nbase + wn * 64 + j * 16 + ln;
                C[row * (size_t)ldc + col] = (OutT)acc[i][j][r];
            }
}

// ---------------------------------------------------------------------------
// Attention over fused buffer, RoPE fused in. One workgroup per (b,h).
// Ks LDS holds roped K for phase 1, then is reused to hold P for phase 2.
// ---------------------------------------------------------------------------
__global__ __launch_bounds__(256) void attn_kernel(bf16* __restrict__ buf)
{
    __shared__ __align__(16) bf16 KP_lds[128 * 136];  // roped K, then P
    __shared__ __align__(16) bf16 Vt_lds[128 * 136];  // Vt[d][k] = V[k][d]

    const int bh = blockIdx.x;
    const int b  = bh >> 4;
    const int h  = bh & 15;
    const size_t baseQ = (size_t)b * SEQ * LDF + (size_t)h * D_HEAD;
    const size_t baseK = baseQ + KOFF;
    const size_t baseV = baseQ + VOFF;

    const int tid  = threadIdx.x;
    const int w    = tid >> 6;
    const int l    = tid & 63;
    const int quad = l >> 4;
    const int ln   = l & 15;

    // ---- stage roped K rows + V^T: thread -> row k=tid>>1, half d0=(tid&1)*64
    {
        int k  = tid >> 1;
        int d0 = (tid & 1) * 64;
        const bf16* kp = buf + baseK + (size_t)k * LDF + d0;
        const bf16* vp = buf + baseV + (size_t)k * LDF + d0;
        for (int c = 0; c < 8; ++c) {
            bf16x8 kv = *(const bf16x8*)(kp + c * 8);
            *(bf16x8*)&KP_lds[k * 136 + d0 + c * 8] = rope8(kv, k, d0 / 2 + c * 4);
            bf16x8 vv = *(const bf16x8*)(vp + c * 8);
            for (int j = 0; j < 8; ++j)
                Vt_lds[(d0 + c * 8 + j) * 136 + k] = vv[j];
        }
    }
    __syncthreads();

    const float rscale = 0.08838834764831845f;   // 1/sqrt(128)
    const float NEG    = -1e30f;

    // ---- phase 1: S = ropeQ @ ropeK^T for both strips, softmax in regs ----
    f32x4 acc2[2][8];
    for (int s = 0; s < 2; ++s)
        for (int nt = 0; nt < 8; ++nt) acc2[s][nt] = (f32x4){0.f, 0.f, 0.f, 0.f};

    for (int s = 0; s < 2; ++s) {
        const int q0 = w * 32 + s * 16;
        for (int kt = 0; kt < 4; ++kt) {
            bf16x8 qa = *(const bf16x8*)(buf + baseQ + (size_t)(q0 + ln) * LDF
                                           + kt * 32 + quad * 8);
            bf16x8 a = rope8(qa, q0 + ln, kt * 16 + quad * 4);
            for (int nt = 0; nt < 8; ++nt) {
                bf16x8 bb = *(const bf16x8*)&KP_lds[(nt * 16 + ln) * 136
                                                    + kt * 32 + quad * 8];
                acc2[s][nt] = mfma16(a, bb, acc2[s][nt]);
            }
        }

        float mx[4] = {NEG, NEG, NEG, NEG};
        for (int nt = 0; nt < 8; ++nt)
            for (int r = 0; r < 4; ++r) {
                int q = q0 + quad * 4 + r;
                int c = nt * 16 + ln;
                float v = acc2[s][nt][r] * rscale;
                v = (c <= q) ? v : NEG;
                acc2[s][nt][r] = v;
                mx[r] = fmaxf(mx[r], v);
            }
        for (int m = 1; m < 16; m <<= 1)
            for (int r = 0; r < 4; ++r)
                mx[r] = fmaxf(mx[r], __shfl_xor(mx[r], m));

        float sm[4] = {0.f, 0.f, 0.f, 0.f};
        for (int nt = 0; nt < 8; ++nt)
            for (int r = 0; r < 4; ++r) {
                float p = __expf(acc2[s][nt][r] - mx[r]);
                acc2[s][nt][r] = p;
                sm[r] += p;
            }
        for (int m = 1; m < 16; m <<= 1)
            for (int r = 0; r < 4; ++r)
                sm[r] += __shfl_xor(sm[r], m);

        for (int r = 0; r < 4; ++r) sm[r] = 1.0f / sm[r];
        for (int nt = 0; nt < 8; ++nt)
            for (int r = 0; r < 4; ++r)
                acc2[s][nt][r] *= sm[r];
    }

    __syncthreads();   // all K reads from KP_lds complete

    // ---- write P over the K region (own-wave rows only) ----
    for (int s = 0; s < 2; ++s)
        for (int nt = 0; nt < 8; ++nt)
            for (int r = 0; r < 4; ++r) {
                int q = w * 32 + s * 16 + quad * 4 + r;
                int c = nt * 16 + ln;
                KP_lds[q * 136 + c] = (bf16)acc2[s][nt][r];
            }

    // ---- phase 2: O = P @ V (P rows are own-wave; lgkmcnt orders w->r) ----
    f32x4 o[2][8];
    for (int s = 0; s < 2; ++s)
        for (int nt = 0; nt < 8; ++nt) o[s][nt] = (f32x4){0.f, 0.f, 0.f, 0.f};

    for (int kt = 0; kt < 4; ++kt) {
        bf16x8 a0 = *(const bf16x8*)&KP_lds[(w * 32 +      ln) * 136 + kt * 32 + quad * 8];
        bf16x8 a1 = *(const bf16x8*)&KP_lds[(w * 32 + 16 + ln) * 136 + kt * 32 + quad * 8];
        for (int nt = 0; nt < 8; ++nt) {
            bf16x8 bb = *(const bf16x8*)&Vt_lds[(nt * 16 + ln) * 136 + kt * 32 + quad * 8];
            o[0][nt] = mfma16(a0, bb, o[0][nt]);
            o[1][nt] = mfma16(a1, bb, o[1][nt]);
        }
    }

    for (int s = 0; s < 2; ++s)
        for (int nt = 0; nt < 8; ++nt)
            for (int r = 0; r < 4; ++r) {
                int q = w * 32 + s * 16 + quad * 4 + r;
                int d = nt * 16 + ln;
                buf[baseQ + (size_t)q * LDF + d] = (bf16)o[s][nt][r];
            }
}

// ---------------------------------------------------------------------------
extern "C" void kernel_launch(void* const* d_in, const int* in_sizes, int n_in,
                              void* d_out, int out_size, void* d_ws, size_t ws_size,
                              hipStream_t stream)
{
    const float* x  = (const float*)d_in[0];
    const float* Wq = (const float*)d_in[1];
    const float* Wk = (const float*)d_in[2];
    const float* Wv = (const float*)d_in[3];
    const float* Wo = (const float*)d_in[4];
    float* out = (float*)d_out;

    // ws layout (bf16 elems): QKV 100.7 MB | xb 33.6 MB (WoB reuses) | WB 25.2 MB
    bf16* QKV = (bf16*)d_ws;
    bf16* xb  = QKV + (size_t)BT * LDF;
    bf16* WB  = xb + (size_t)BT * D_MODEL;
    bf16* WoB = xb;                               // free after QKV GEMM

    const int n8x = BT * D_MODEL / 8;             // 2,097,152
    const int n8w = D_MODEL * D_MODEL / 8;        //   524,288 = 2^19

    cvt_kernel<<<(n8x + 255) / 256, 256, 0, stream>>>(x, xb, n8x);
    cvt_w3<<<(3 * n8w) / 256, 256, 0, stream>>>(Wq, Wk, Wv, WB);

    // fused QKV projection: [8192 x 6144] = xb @ WB^T
    dim3 g1(LDF / 128, BT / 128);   // (48, 64)
    gemm128<bf16><<<g1, 256, 0, stream>>>(xb, WB, QKV, D_MODEL, D_MODEL, LDF, D_MODEL);

    cvt_kernel<<<(n8w + 255) / 256, 256, 0, stream>>>(Wo, WoB, n8w);

    // attention with fused RoPE; O in-place over Q columns
    attn_kernel<<<BATCH * N_HEADS, 256, 0, stream>>>(QKV);

    // output projection: out[8192 x 2048] = O @ Wo^T (fp32 out)
    dim3 g2(D_MODEL / 128, BT / 128);  // (16, 64)
    gemm128<float><<<g2, 256, 0, stream>>>(QKV, WoB, out, LDF, D_MODEL, D_MODEL, D_MODEL);
}